// Round 2
// baseline (535.538 us; speedup 1.0000x reference)
//
#include <hip/hip_runtime.h>
#include <hip/hip_bf16.h>
#include <math.h>

typedef float floatx4 __attribute__((ext_vector_type(4)));
typedef __bf16 bf16x8 __attribute__((ext_vector_type(8)));
typedef unsigned short ushort_t;

__device__ __forceinline__ ushort_t f2bf(float f) {
    union { float f; unsigned int i; } v; v.f = f;
    unsigned int i = v.i;
    return (ushort_t)((i + 0x7FFFu + ((i >> 16) & 1u)) >> 16);  // RNE, inputs finite
}
__device__ __forceinline__ unsigned int pack2(float a, float b) {
    return (unsigned int)f2bf(a) | ((unsigned int)f2bf(b) << 16);
}
__device__ __forceinline__ floatx4 mfma16(bf16x8 a, bf16x8 b, floatx4 c) {
    return __builtin_amdgcn_mfma_f32_16x16x32_bf16(a, b, c, 0, 0, 0);
}
// async global->LDS, 16B/lane; g is PER-LANE address, lds base wave-uniform,
// lane i lands at lds_base + i*16 bytes
__device__ __forceinline__ void load_lds16(const ushort_t* g, ushort_t* l) {
    __builtin_amdgcn_global_load_lds(
        (const __attribute__((address_space(1))) unsigned int*)g,
        (__attribute__((address_space(3))) unsigned int*)l, 16, 0, 0);
}

// ---------------- fp32 -> bf16 conversion of activations (q,k,v,loc), 3200x2048 each
__global__ __launch_bounds__(256) void k_convert(const float* __restrict__ q, const float* __restrict__ k,
                          const float* __restrict__ v, const float* __restrict__ loc,
                          ushort_t* qb, ushort_t* kb, ushort_t* vb, ushort_t* locb) {
    int z = blockIdx.y;
    const float* src = z == 0 ? q : z == 1 ? k : z == 2 ? v : loc;
    ushort_t* dst    = z == 0 ? qb : z == 1 ? kb : z == 2 ? vb : locb;
    size_t idx = (size_t)blockIdx.x * 256 + threadIdx.x;
    floatx4 f = *(const floatx4*)(src + idx * 4);
    uint2 o;
    o.x = pack2(f[0], f[1]);
    o.y = pack2(f[2], f[3]);
    *(uint2*)(dst + idx * 4) = o;
}

// ---------------- Weight transpose+convert: W (2048x2048 fp32, KxN) -> Wt (NxK bf16)
__global__ void k_wtrans(const float* __restrict__ w0, const float* __restrict__ w1,
                         const float* __restrict__ w2, const float* __restrict__ w3,
                         const float* __restrict__ w4,
                         ushort_t* t0, ushort_t* t1, ushort_t* t2, ushort_t* t3, ushort_t* t4) {
    __shared__ float tile[32][33];
    int z = blockIdx.z;
    const float* W = z == 0 ? w0 : z == 1 ? w1 : z == 2 ? w2 : z == 3 ? w3 : w4;
    ushort_t* T    = z == 0 ? t0 : z == 1 ? t1 : z == 2 ? t2 : z == 3 ? t3 : t4;
    int n0 = blockIdx.x * 32, k0 = blockIdx.y * 32;
    int tx = threadIdx.x & 31, ty = threadIdx.x >> 5;
#pragma unroll
    for (int i = 0; i < 4; i++) {
        int row = ty + i * 8;
        tile[row][tx] = W[(size_t)(k0 + row) * 2048 + n0 + tx];
    }
    __syncthreads();
#pragma unroll
    for (int i = 0; i < 4; i++) {
        int row = ty + i * 8;
        T[(size_t)(n0 + row) * 2048 + k0 + tx] = f2bf(tile[tx][row]);
    }
}

// ---------------- lv (3200x2048 bf16) -> lvT ([b][h][t] padded t->224, zeros)
__global__ void k_vtrans(const ushort_t* __restrict__ lv, ushort_t* __restrict__ lvT) {
    __shared__ ushort_t tile[32][33];
    int n0 = blockIdx.x * 32;
    int t0 = blockIdx.y * 32;
    int b = blockIdx.z;
    int tx = threadIdx.x & 31, ty = threadIdx.x >> 5;
#pragma unroll
    for (int i = 0; i < 4; i++) {
        int row = ty + i * 8;
        int tk = t0 + row;
        ushort_t v = 0;
        if (tk < 200) v = lv[(size_t)(b * 200 + tk) * 2048 + n0 + tx];
        tile[row][tx] = v;
    }
    __syncthreads();
#pragma unroll
    for (int i = 0; i < 4; i++) {
        int row = ty + i * 8;
        lvT[((size_t)b * 2048 + n0 + row) * 224 + t0 + tx] = tile[tx][row];
    }
}

// ---------------- Batched projection GEMM — 8-phase schedule (T2+T3+T4+T5), 256x256 tile,
// BK=64, 128 KiB LDS double-buffer, 8 waves (2M x 4N), counted vmcnt (never drained in loop).
// Per K-tile: 4 phases, quadrant order (M0,N0)(M0,N1)(M1,N1)(M1,N0).
// Staging stream: B(t+1) -> other buf at P1/P2; A(t+2) -> current buf at P4 (A dead after P3).
// vmcnt(4) once per K-tile at P4: retires tile t+1's 8 loads, keeps A(t+2)'s 4 in flight.
// z=0 -> lqp, z=1 -> kcat[:, 0:2048], z=2 -> lvp, z=3 -> llocp, z=4 -> kcat[:, 2048:4096]
#define G_SB   __builtin_amdgcn_sched_barrier(0)
#define G_BAR  __builtin_amdgcn_s_barrier()
#define WAITL0 asm volatile("s_waitcnt lgkmcnt(0)" ::: "memory")
#define WAITL8 asm volatile("s_waitcnt lgkmcnt(8)" ::: "memory")
#define WVM4   asm volatile("s_waitcnt vmcnt(4)" ::: "memory")
#define WVM0   asm volatile("s_waitcnt vmcnt(0)" ::: "memory")

__global__ __launch_bounds__(512, 2) void k_gemm(
    const ushort_t* A0, const ushort_t* A1, const ushort_t* A2, const ushort_t* A3, const ushort_t* A4,
    const ushort_t* W0, const ushort_t* W1, const ushort_t* W2, const ushort_t* W3, const ushort_t* W4,
    const float* B0, const float* B1, const float* B2, const float* B3, const float* B4,
    ushort_t* lqp, ushort_t* lvp, ushort_t* llocp, ushort_t* kcat) {
    // 520 workgroups = 8 XCDs x 65; bijective XCD swizzle (nwg % 8 == 0)
    int wg = blockIdx.x;
    int swz = (wg & 7) * 65 + (wg >> 3);
    int z = swz / 104;                 // 13 m-tiles x 8 n-tiles = 104 per z
    int rem = swz - z * 104;
    int ntile = rem / 13;              // n-major: consecutive blocks share B-panel
    int mtile = rem - ntile * 13;
    int m0 = mtile * 256, n0 = ntile * 256;

    const ushort_t* A  = z == 0 ? A0 : z == 1 ? A1 : z == 2 ? A2 : z == 3 ? A3 : A4;
    const ushort_t* Wt = z == 0 ? W0 : z == 1 ? W1 : z == 2 ? W2 : z == 3 ? W3 : W4;
    const float* bias  = z == 0 ? B0 : z == 1 ? B1 : z == 2 ? B2 : z == 3 ? B3 : B4;

    __shared__ ushort_t AsF[2 * 256 * 64];   // 64 KB (2 buffers)
    __shared__ ushort_t BsF[2 * 256 * 64];   // 64 KB

    int tid = threadIdx.x;
    int lane = tid & 63, w = tid >> 6;
    int quad = lane >> 4, col = lane & 15;
    int wr = w >> 2, wc = w & 3;

    // --- staging: each gload covers 64 rows x 64 cols (8 waves x 8 rows x 128 B).
    // LDS written linearly; XOR swizzle (chunk ^= row&7) applied on the GLOBAL source:
    // lane l (row sl=l>>3, lds-chunk l&7) fetches global chunk (l&7)^sl. Slab bases are
    // multiples of 8 rows, so the swizzle is lane-pure.
    int sl = lane >> 3;
    int sc = ((lane & 7) ^ sl) * 8;        // element offset of swizzled 16B chunk
    const ushort_t* Ag[4]; const ushort_t* Bg[4]; int ldst[4];
#pragma unroll
    for (int u = 0; u < 4; u++) {          // u = half*2 + gload
        int rowoff = (u >> 1) * 128 + (u & 1) * 64 + w * 8;
        Ag[u] = A  + (size_t)(m0 + rowoff + sl) * 2048 + sc;
        Bg[u] = Wt + (size_t)(n0 + rowoff + sl) * 2048 + sc;
        ldst[u] = rowoff * 64;             // element offset inside one buffer
    }

#define STG_A(KT, BUF) do { int kk = (KT) * 64;                       \
        load_lds16(Ag[0] + kk, AsF + (BUF) * 16384 + ldst[0]);        \
        load_lds16(Ag[1] + kk, AsF + (BUF) * 16384 + ldst[1]);        \
        load_lds16(Ag[2] + kk, AsF + (BUF) * 16384 + ldst[2]);        \
        load_lds16(Ag[3] + kk, AsF + (BUF) * 16384 + ldst[3]); } while (0)
#define STG_BLO(KT, BUF) do { int kk = (KT) * 64;                     \
        load_lds16(Bg[0] + kk, BsF + (BUF) * 16384 + ldst[0]);        \
        load_lds16(Bg[1] + kk, BsF + (BUF) * 16384 + ldst[1]); } while (0)
#define STG_BHI(KT, BUF) do { int kk = (KT) * 64;                     \
        load_lds16(Bg[2] + kk, BsF + (BUF) * 16384 + ldst[2]);        \
        load_lds16(Bg[3] + kk, BsF + (BUF) * 16384 + ldst[3]); } while (0)

    // --- ds_read offsets (elements). frag(row, ks): row*64 + ((ks*4+quad)^(col&7))*8.
    // row&7 == col&7 for all frag rows (bases are multiples of 16) -> matches stage swizzle.
    int sw = col & 7;
    int ko0 = (quad ^ sw) * 8;
    int ko1 = ((4 | quad) ^ sw) * 8;
    int aro[8], bro[4];
#pragma unroll
    for (int mi = 0; mi < 8; mi++) aro[mi] = (wr * 128 + mi * 16 + col) * 64;
#pragma unroll
    for (int ni = 0; ni < 4; ni++) bro[ni] = (wc * 64 + ni * 16 + col) * 64;

    bf16x8 af[4][2], bfr[2][2];
    floatx4 acc[8][4] = {};

#define RD_A(J, MI, BUF) do {                                         \
        const ushort_t* p_ = AsF + (BUF) * 16384 + aro[MI];           \
        af[J][0] = *(const bf16x8*)(p_ + ko0);                        \
        af[J][1] = *(const bf16x8*)(p_ + ko1); } while (0)
#define RD_B(J, NI, BUF) do {                                         \
        const ushort_t* p_ = BsF + (BUF) * 16384 + bro[NI];           \
        bfr[J][0] = *(const bf16x8*)(p_ + ko0);                       \
        bfr[J][1] = *(const bf16x8*)(p_ + ko1); } while (0)
#define QMFMA(MH, NB) do {                                            \
        __builtin_amdgcn_s_setprio(1);                                \
        _Pragma("unroll") for (int mi = 0; mi < 4; mi++)              \
        _Pragma("unroll") for (int nj = 0; nj < 2; nj++) {            \
            acc[(MH) * 4 + mi][(NB) + nj] =                           \
                mfma16(af[mi][0], bfr[nj][0], acc[(MH) * 4 + mi][(NB) + nj]); \
            acc[(MH) * 4 + mi][(NB) + nj] =                           \
                mfma16(af[mi][1], bfr[nj][1], acc[(MH) * 4 + mi][(NB) + nj]); } \
        __builtin_amdgcn_s_setprio(0); } while (0)

    // --- prologue: A(0),B(0),A(1) staged (12 loads); wait so tile 0 landed, A(1) in flight.
    STG_A(0, 0); STG_BLO(0, 0); STG_BHI(0, 0); STG_A(1, 1);
    WVM4; G_SB; G_BAR; G_SB;

#pragma unroll 1
    for (int t = 0; t < 32; t++) {
        int c = t & 1, o = c ^ 1;
        int tB = (t + 1) & 31;   // wrap keeps vmcnt math static; extra stages are in-bounds
        int tA = (t + 2) & 31;   //   writes to regions nothing reads afterwards
        // P1: read A-mh0(8) + B-nh0(4); stage B-lo(t+1) -> other
        RD_A(0, 0, c); RD_A(1, 1, c); RD_A(2, 2, c); RD_A(3, 3, c);
        RD_B(0, 0, c); RD_B(1, 1, c);
        STG_BLO(tB, o);
        WAITL8;
        G_SB; G_BAR; WAITL0; G_SB;
        QMFMA(0, 0);
        G_SB; G_BAR;
        // P2: read B-nh1(4); stage B-hi(t+1) -> other
        RD_B(0, 2, c); RD_B(1, 3, c);
        STG_BHI(tB, o);
        G_SB; G_BAR; WAITL0; G_SB;
        QMFMA(0, 2);
        G_SB; G_BAR;
        // P3: read A-mh1(8)
        RD_A(0, 4, c); RD_A(1, 5, c); RD_A(2, 6, c); RD_A(3, 7, c);
        G_SB; G_BAR; WAITL0; G_SB;
        QMFMA(1, 2);
        G_SB; G_BAR;
        // P4: re-read B-nh0(4); stage A(t+2) -> current (A regions dead after P3); vmcnt(4)
        RD_B(0, 0, c); RD_B(1, 1, c);
        STG_A(tA, c);
        WVM4;
        G_SB; G_BAR; WAITL0; G_SB;
        QMFMA(1, 0);
        G_SB; G_BAR;
    }
    WVM0;   // drain wrap-staging before endpgm

    // --- epilogue: bias add, bf16 convert, store (rows >= 3200 are padding -> guarded)
    ushort_t* Cplain = z == 0 ? lqp : z == 2 ? lvp : llocp;
    int kcoff = (z == 4) ? 2048 : 0;
    bool to_kcat = (z == 1 || z == 4);
    float bvv[4];
#pragma unroll
    for (int ni = 0; ni < 4; ni++) bvv[ni] = bias[n0 + wc * 64 + ni * 16 + col];
#pragma unroll
    for (int mi = 0; mi < 8; mi++) {
#pragma unroll
        for (int r = 0; r < 4; r++) {
            int m = m0 + wr * 128 + mi * 16 + quad * 4 + r;
            if (m < 3200) {
                ushort_t* crow;
                if (to_kcat) {
                    int bb = m / 200, rr = m - bb * 200;
                    crow = kcat + (size_t)(bb * 224 + rr) * 4096 + kcoff;
                } else {
                    crow = Cplain + (size_t)m * 2048;
                }
#pragma unroll
                for (int ni = 0; ni < 4; ni++) {
                    int n = n0 + wc * 64 + ni * 16 + col;
                    crow[n] = f2bf(acc[mi][ni][r] + bvv[ni]);
                }
            }
        }
    }
#undef STG_A
#undef STG_BLO
#undef STG_BHI
#undef RD_A
#undef RD_B
#undef QMFMA
}

// ---------------- qcat[b][r][0:2048] = lq + param ; qcat[b][r][2048:] = lq + lloc
__global__ __launch_bounds__(256) void k_qprep(const ushort_t* __restrict__ lqp,
                                               const ushort_t* __restrict__ llocp,
                                               const float* __restrict__ param,
                                               ushort_t* __restrict__ qcat) {
    int m = blockIdx.x;           // 0..3199
    int b = m / 200, r = m - b * 200;
    int c = threadIdx.x * 8;
    bf16x8 ql = *(const bf16x8*)(lqp + (size_t)m * 2048 + c);
    bf16x8 ll = *(const bf16x8*)(llocp + (size_t)m * 2048 + c);
    floatx4 p0 = *(const floatx4*)(param + (size_t)m * 2048 + c);
    floatx4 p1 = *(const floatx4*)(param + (size_t)m * 2048 + c + 4);
    bf16x8 q1, q2;
#pragma unroll
    for (int j = 0; j < 4; j++) {
        q1[j]     = (__bf16)((float)ql[j] + p0[j]);
        q1[j + 4] = (__bf16)((float)ql[j + 4] + p1[j]);
        q2[j]     = (__bf16)((float)ql[j] + (float)ll[j]);
        q2[j + 4] = (__bf16)((float)ql[j + 4] + (float)ll[j + 4]);
    }
    ushort_t* dst = qcat + ((size_t)(b * 224 + r)) * 4096 + c;
    *(bf16x8*)dst = q1;
    *(bf16x8*)(dst + 2048) = q2;
}

// ---------------- Scores (K-split): part[kc][b][row 0..223][key 0..223] fp32 partial
// grid (7 qt x 16 b x 2 kc), 256 thr; 32 q-rows x 224 keys, K=2048 per block
__global__ __launch_bounds__(256) void k_scores(const ushort_t* __restrict__ qcat,
                                                const ushort_t* __restrict__ kcat,
                                                float* __restrict__ part) {
    int qt = blockIdx.x;   // 0..6
    int b  = blockIdx.y;   // 0..15
    int kc = blockIdx.z;   // 0..1
    __shared__ ushort_t As[32 * 32];    // 2 KB
    __shared__ ushort_t Bs[224 * 32];   // 14 KB

    int tid = threadIdx.x;
    int lane = tid & 63, w = tid >> 6;
    int quad = lane >> 4, col = lane & 15;
    int srow = lane >> 2, scol = (lane & 3) * 8;

    const ushort_t* qbase = qcat + ((size_t)b * 224 + qt * 32) * 4096 + kc * 2048;
    const ushort_t* kbase = kcat + (size_t)b * 224 * 4096 + kc * 2048;

    const ushort_t* ssrc[4];
    ushort_t* sdst[4];
#pragma unroll
    for (int o = 0; o < 4; o++) {
        int id = w * 4 + o;
        if (id < 14) {
            ssrc[o] = kbase + (size_t)(id * 16 + srow) * 4096 + scol;
            sdst[o] = Bs + id * 512;
        } else {
            ssrc[o] = qbase + (size_t)((id - 14) * 16 + srow) * 4096 + scol;
            sdst[o] = As + (id - 14) * 512;
        }
    }

    floatx4 acc[2][4] = {};
    for (int k0 = 0; k0 < 2048; k0 += 32) {
        __syncthreads();
#pragma unroll
        for (int o = 0; o < 4; o++) load_lds16(ssrc[o] + k0, sdst[o]);
        __syncthreads();
        bf16x8 af[2];
#pragma unroll
        for (int mi = 0; mi < 2; mi++) af[mi] = *(const bf16x8*)&As[(mi * 16 + col) * 32 + quad * 8];
#pragma unroll
        for (int fi = 0; fi < 4; fi++) {
            int f = w + fi * 4;
            if (f < 14) {
                bf16x8 bf = *(const bf16x8*)&Bs[(f * 16 + col) * 32 + quad * 8];
#pragma unroll
                for (int mi = 0; mi < 2; mi++) acc[mi][fi] = mfma16(af[mi], bf, acc[mi][fi]);
            }
        }
    }

    float* pbase = part + ((size_t)(kc * 16 + b) * 224 + qt * 32) * 224;
#pragma unroll
    for (int fi = 0; fi < 4; fi++) {
        int f = w + fi * 4;
        if (f < 14) {
#pragma unroll
            for (int mi = 0; mi < 2; mi++)
#pragma unroll
                for (int r = 0; r < 4; r++)
                    pbase[(mi * 16 + quad * 4 + r) * 224 + f * 16 + col] = acc[mi][fi][r];
        }
    }
}

// ---------------- softmax over summed partials -> attn bf16 [b][200][224], cols>=200 zero
// grid 400 blocks x 256 thr; 8 rows/block, 32 threads/row, 7 cols/thread
__global__ __launch_bounds__(256) void k_softmax(const float* __restrict__ part,
                                                 ushort_t* __restrict__ attn) {
    int row = blockIdx.x * 8 + (threadIdx.x >> 5);  // 0..3199
    int b = row / 200, r = row - b * 200;
    int p = threadIdx.x & 31;
    const float* p0 = part + ((size_t)b * 224 + r) * 224;
    const float* p1 = p0 + (size_t)16 * 224 * 224;
    const float scale = 0.022097086912079608f;  // 1/sqrt(2048)
    float ev[7];
    float mx = -1e30f;
#pragma unroll
    for (int j = 0; j < 7; j++) {
        int c = p * 7 + j;
        float v = (c < 200) ? (p0[c] + p1[c]) * scale : -1e30f;
        ev[j] = v;
        mx = fmaxf(mx, v);
    }
#pragma unroll
    for (int m = 1; m < 32; m <<= 1) mx = fmaxf(mx, __shfl_xor(mx, m, 32));
    float s = 0.f;
#pragma unroll
    for (int j = 0; j < 7; j++) {
        float e = __expf(ev[j] - mx);
        ev[j] = e;
        s += e;
    }
#pragma unroll
    for (int m = 1; m < 32; m <<= 1) s += __shfl_xor(s, m, 32);
    float rs = 1.0f / s;
    ushort_t* arow = attn + (size_t)row * 224;
#pragma unroll
    for (int j = 0; j < 7; j++) {
        int c = p * 7 + j;
        arow[c] = (c < 200) ? f2bf(ev[j] * rs) : (ushort_t)0;
    }
}

// ---------------- out[b][m][n] = attn[b][m][:] @ lv  (via lvT), fp32 out
__global__ __launch_bounds__(256) void k_pv(const ushort_t* __restrict__ attn,
                                            const ushort_t* __restrict__ lvT,
                                            float* __restrict__ out) {
    int nt = blockIdx.x;  // 0..15 (128 cols each)
    int qt = blockIdx.y;  // 0..12 (16 rows each)
    int b = blockIdx.z;
    int tid = threadIdx.x, lane = tid & 63, w = tid >> 6;
    int quad = lane >> 4, col = lane & 15;
    int aq = qt * 16 + col; if (aq > 199) aq = 199;
    const ushort_t* arow = attn + (size_t)(b * 200 + aq) * 224;
    int nbase = nt * 128 + w * 32;
    const ushort_t* bp0 = lvT + ((size_t)b * 2048 + nbase + col) * 224;
    const ushort_t* bp1 = lvT + ((size_t)b * 2048 + nbase + 16 + col) * 224;
    floatx4 acc[2] = {};
#pragma unroll
    for (int k0 = 0; k0 < 224; k0 += 32) {
        int ko = k0 + quad * 8;
        bf16x8 av = *(const bf16x8*)(arow + ko);
        bf16x8 b0 = *(const bf16x8*)(bp0 + ko);
        bf16x8 b1 = *(const bf16x8*)(bp1 + ko);
        acc[0] = mfma16(av, b0, acc[0]);
        acc[1] = mfma16(av, b1, acc[1]);
    }
#pragma unroll
    for (int f = 0; f < 2; f++) {
        int n = nbase + f * 16 + col;
#pragma unroll
        for (int r = 0; r < 4; r++) {
            int m = qt * 16 + quad * 4 + r;
            if (m < 200) out[(size_t)(b * 200 + m) * 2048 + n] = acc[f][r];
        }
    }
}

extern "C" void kernel_launch(void* const* d_in, const int* in_sizes, int n_in,
                              void* d_out, int out_size, void* d_ws, size_t ws_size,
                              hipStream_t stream) {
    (void)in_sizes; (void)n_in; (void)out_size; (void)ws_size;
    const float* q    = (const float*)d_in[0];
    const float* k    = (const float*)d_in[1];
    const float* v    = (const float*)d_in[2];
    const float* loc  = (const float*)d_in[3];
    const float* Wq   = (const float*)d_in[4];
    const float* bq   = (const float*)d_in[5];
    const float* Wk   = (const float*)d_in[6];
    const float* bk   = (const float*)d_in[7];
    const float* Wv   = (const float*)d_in[8];
    const float* bv   = (const float*)d_in[9];
    const float* Wloc = (const float*)d_in[10];
    const float* bloc = (const float*)d_in[11];
    const float* Wlk  = (const float*)d_in[12];
    const float* blk  = (const float*)d_in[13];
    const float* param = (const float*)d_in[14];
    float* out = (float*)d_out;

    size_t off = 0;
    auto nxt = [&](size_t bytes) {
        void* p = (char*)d_ws + off;
        off += (bytes + 255) & ~(size_t)255;
        return p;
    };
    ushort_t* wt[5];
    for (int i = 0; i < 5; i++) wt[i] = (ushort_t*)nxt(2048ull * 2048 * 2);
    ushort_t* qb    = (ushort_t*)nxt(3200ull * 2048 * 2);
    ushort_t* kb    = (ushort_t*)nxt(3200ull * 2048 * 2);
    ushort_t* vb    = (ushort_t*)nxt(3200ull * 2048 * 2);
    ushort_t* locb  = (ushort_t*)nxt(3200ull * 2048 * 2);
    ushort_t* lqp   = (ushort_t*)nxt(3200ull * 2048 * 2);
    ushort_t* llocp = (ushort_t*)nxt(3200ull * 2048 * 2);
    ushort_t* lvp   = (ushort_t*)nxt(3200ull * 2048 * 2);
    ushort_t* kcat  = (ushort_t*)nxt(16ull * 224 * 4096 * 2);
    // overlays (wt region = 41.9 MB, dead after k_gemm):
    ushort_t* lvT  = wt[0];                               // bytes 0 .. 14.7 MB
    ushort_t* attn = wt[0] + 16ull * 2048 * 224;          // 14.7 .. 16.1 MB
    float*    part = (float*)((char*)d_ws + 2ull * 2048 * 2048 * 2);  // 16.8 .. 23.2 MB (wt[2]+)
    ushort_t* qcat = qb;   // 29.4 MB into 52.4 MB conv region

    k_convert<<<dim3(6400, 4), 256, 0, stream>>>(q, k, v, loc, qb, kb, vb, locb);
    k_wtrans<<<dim3(64, 64, 5), 256, 0, stream>>>(Wq, Wk, Wv, Wloc, Wlk,
                                                  wt[0], wt[1], wt[2], wt[3], wt[4]);
    // 13 m-tiles x 8 n-tiles x 5 z = 520 blocks (8 XCDs x 65). M padded to 3328:
    // out-of-range rows read into the adjacent workspace buffer (in-bounds garbage),
    // stores are guarded by m < 3200.
    k_gemm<<<dim3(520), 512, 0, stream>>>(qb, kb, vb, locb, locb,
                                          wt[0], wt[1], wt[2], wt[3], wt[4],
                                          bq, bk, bv, bloc, blk,
                                          lqp, lvp, llocp, kcat);
    k_qprep<<<dim3(3200), 256, 0, stream>>>(lqp, llocp, param, qcat);
    k_vtrans<<<dim3(64, 7, 16), 256, 0, stream>>>(lvp, lvT);
    k_scores<<<dim3(7, 16, 2), 256, 0, stream>>>(qcat, kcat, part);
    k_softmax<<<dim3(400), 256, 0, stream>>>(part, attn);
    k_pv<<<dim3(16, 13, 16), 256, 0, stream>>>(attn, lvT, out);
}

// Round 3
// 472.229 us; speedup vs baseline: 1.1341x; 1.1341x over previous
//
#include <hip/hip_runtime.h>
#include <hip/hip_bf16.h>
#include <math.h>

typedef float floatx4 __attribute__((ext_vector_type(4)));
typedef __bf16 bf16x8 __attribute__((ext_vector_type(8)));
typedef unsigned short ushort_t;

__device__ __forceinline__ ushort_t f2bf(float f) {
    union { float f; unsigned int i; } v; v.f = f;
    unsigned int i = v.i;
    return (ushort_t)((i + 0x7FFFu + ((i >> 16) & 1u)) >> 16);  // RNE, inputs finite
}
__device__ __forceinline__ unsigned int pack2(float a, float b) {
    return (unsigned int)f2bf(a) | ((unsigned int)f2bf(b) << 16);
}
__device__ __forceinline__ floatx4 mfma16(bf16x8 a, bf16x8 b, floatx4 c) {
    return __builtin_amdgcn_mfma_f32_16x16x32_bf16(a, b, c, 0, 0, 0);
}
// async global->LDS, 16B/lane; g is PER-LANE address, lds base wave-uniform,
// lane i lands at lds_base + i*16 bytes
__device__ __forceinline__ void load_lds16(const ushort_t* g, ushort_t* l) {
    __builtin_amdgcn_global_load_lds(
        (const __attribute__((address_space(1))) unsigned int*)g,
        (__attribute__((address_space(3))) unsigned int*)l, 16, 0, 0);
}

// ---------------- fp32 -> bf16 conversion of activations (q,k,v,loc), 3200x2048 each
__global__ __launch_bounds__(256) void k_convert(const float* __restrict__ q, const float* __restrict__ k,
                          const float* __restrict__ v, const float* __restrict__ loc,
                          ushort_t* qb, ushort_t* kb, ushort_t* vb, ushort_t* locb) {
    int z = blockIdx.y;
    const float* src = z == 0 ? q : z == 1 ? k : z == 2 ? v : loc;
    ushort_t* dst    = z == 0 ? qb : z == 1 ? kb : z == 2 ? vb : locb;
    size_t idx = (size_t)blockIdx.x * 256 + threadIdx.x;
    floatx4 f = *(const floatx4*)(src + idx * 4);
    uint2 o;
    o.x = pack2(f[0], f[1]);
    o.y = pack2(f[2], f[3]);
    *(uint2*)(dst + idx * 4) = o;
}

// ---------------- Weight transpose+convert: W (2048x2048 fp32, KxN) -> Wt (NxK bf16)
__global__ void k_wtrans(const float* __restrict__ w0, const float* __restrict__ w1,
                         const float* __restrict__ w2, const float* __restrict__ w3,
                         const float* __restrict__ w4,
                         ushort_t* t0, ushort_t* t1, ushort_t* t2, ushort_t* t3, ushort_t* t4) {
    __shared__ float tile[32][33];
    int z = blockIdx.z;
    const float* W = z == 0 ? w0 : z == 1 ? w1 : z == 2 ? w2 : z == 3 ? w3 : w4;
    ushort_t* T    = z == 0 ? t0 : z == 1 ? t1 : z == 2 ? t2 : z == 3 ? t3 : t4;
    int n0 = blockIdx.x * 32, k0 = blockIdx.y * 32;
    int tx = threadIdx.x & 31, ty = threadIdx.x >> 5;
#pragma unroll
    for (int i = 0; i < 4; i++) {
        int row = ty + i * 8;
        tile[row][tx] = W[(size_t)(k0 + row) * 2048 + n0 + tx];
    }
    __syncthreads();
#pragma unroll
    for (int i = 0; i < 4; i++) {
        int row = ty + i * 8;
        T[(size_t)(n0 + row) * 2048 + k0 + tx] = f2bf(tile[tx][row]);
    }
}

// ---------------- lv (3200x2048 bf16) -> lvT ([b][h][t] padded t->224, zeros)
__global__ void k_vtrans(const ushort_t* __restrict__ lv, ushort_t* __restrict__ lvT) {
    __shared__ ushort_t tile[32][33];
    int n0 = blockIdx.x * 32;
    int t0 = blockIdx.y * 32;
    int b = blockIdx.z;
    int tx = threadIdx.x & 31, ty = threadIdx.x >> 5;
#pragma unroll
    for (int i = 0; i < 4; i++) {
        int row = ty + i * 8;
        int tk = t0 + row;
        ushort_t v = 0;
        if (tk < 200) v = lv[(size_t)(b * 200 + tk) * 2048 + n0 + tx];
        tile[row][tx] = v;
    }
    __syncthreads();
#pragma unroll
    for (int i = 0; i < 4; i++) {
        int row = ty + i * 8;
        lvT[((size_t)b * 2048 + n0 + row) * 224 + t0 + tx] = tile[tx][row];
    }
}

// ---------------- Batched projection GEMM — 128x128 tile (tail-free fine grid), BK=64,
// 64 KiB LDS double-buffer -> 2 blocks/CU, 4 waves (2M x 2N), counted vmcnt(8) (never 0
// in the loop), XOR-swizzled LDS (0 bank conflicts, proven R1/R2), XCD-aware swizzle.
// M = 3200 = 25x128 exactly (no padding). Grid 2000 = 25m x 16n x 5z = 8 XCDs x 250.
// z=0 -> lqp, z=1 -> kcat[:, 0:2048], z=2 -> lvp, z=3 -> llocp, z=4 -> kcat[:, 2048:4096]
#define G_SB   __builtin_amdgcn_sched_barrier(0)
#define G_BAR  __builtin_amdgcn_s_barrier()
#define WVM8   asm volatile("s_waitcnt vmcnt(8)" ::: "memory")
#define WVM0   asm volatile("s_waitcnt vmcnt(0)" ::: "memory")

__global__ __launch_bounds__(256, 2) void k_gemm(
    const ushort_t* A0, const ushort_t* A1, const ushort_t* A2, const ushort_t* A3, const ushort_t* A4,
    const ushort_t* W0, const ushort_t* W1, const ushort_t* W2, const ushort_t* W3, const ushort_t* W4,
    const float* B0, const float* B1, const float* B2, const float* B3, const float* B4,
    ushort_t* lqp, ushort_t* lvp, ushort_t* llocp, ushort_t* kcat) {
    // 2000 blocks = 8 XCDs x 250; bijective. Within an XCD: m-tiles fastest (25 per
    // n-panel) so the 0.5 MB B-panel stays L2-resident across 25 consecutive blocks.
    int bid = blockIdx.x;
    int tileid = (bid & 7) * 250 + (bid >> 3);
    int z = tileid / 400;              // 25 m x 16 n = 400 tiles per z
    int r = tileid - z * 400;
    int nt = r / 25;
    int mt = r - nt * 25;
    int m0 = mt * 128, n0 = nt * 128;

    const ushort_t* A  = z == 0 ? A0 : z == 1 ? A1 : z == 2 ? A2 : z == 3 ? A3 : A4;
    const ushort_t* Wt = z == 0 ? W0 : z == 1 ? W1 : z == 2 ? W2 : z == 3 ? W3 : W4;
    const float* bias  = z == 0 ? B0 : z == 1 ? B1 : z == 2 ? B2 : z == 3 ? B3 : B4;

    __shared__ ushort_t As[2][128 * 64];   // 16 KB each buffer
    __shared__ ushort_t Bs[2][128 * 64];

    int tid = threadIdx.x;
    int lane = tid & 63, w = tid >> 6;
    int quad = lane >> 4, col = lane & 15;
    int wr = w >> 1, wc = w & 1;

    // --- staging: per gload one wave covers 8 rows x 128 B. 4 slabs/wave for A, 4 for B
    // = 8 gloads/tile/wave. LDS written linearly; XOR swizzle (chunk ^= row&7) applied on
    // the GLOBAL source address: lane l (slab row sl=l>>3, lds-chunk l&7) fetches global
    // chunk (l&7)^sl. Slab bases are multiples of 8 rows -> swizzle is lane-pure.
    int sl = lane >> 3;
    int sc = ((lane & 7) ^ sl) * 8;        // element offset of swizzled 16B chunk
    const ushort_t* Ag[4]; const ushort_t* Bg[4]; int ldst[4];
#pragma unroll
    for (int u = 0; u < 4; u++) {
        int rowoff = u * 32 + w * 8;
        Ag[u] = A  + (size_t)(m0 + rowoff + sl) * 2048 + sc;
        Bg[u] = Wt + (size_t)(n0 + rowoff + sl) * 2048 + sc;
        ldst[u] = rowoff * 64;             // element offset inside one buffer
    }

#define STG(KT, BUF) do { int kk = (KT) * 64;              \
        load_lds16(Ag[0] + kk, As[BUF] + ldst[0]);         \
        load_lds16(Ag[1] + kk, As[BUF] + ldst[1]);         \
        load_lds16(Ag[2] + kk, As[BUF] + ldst[2]);         \
        load_lds16(Ag[3] + kk, As[BUF] + ldst[3]);         \
        load_lds16(Bg[0] + kk, Bs[BUF] + ldst[0]);         \
        load_lds16(Bg[1] + kk, Bs[BUF] + ldst[1]);         \
        load_lds16(Bg[2] + kk, Bs[BUF] + ldst[2]);         \
        load_lds16(Bg[3] + kk, Bs[BUF] + ldst[3]); } while (0)

    // --- ds_read offsets. frag(row, ks): elem row*64 + ((ks*4+quad)^(col&7))*8.
    // row&7 == col&7 (row bases are multiples of 16) -> matches the staging swizzle.
    int sw = col & 7;
    int ko0 = (quad ^ sw) * 8;
    int ko1 = ((4 | quad) ^ sw) * 8;
    int aro[4], bro[4];
#pragma unroll
    for (int mi = 0; mi < 4; mi++) aro[mi] = (wr * 64 + mi * 16 + col) * 64;
#pragma unroll
    for (int ni = 0; ni < 4; ni++) bro[ni] = (wc * 64 + ni * 16 + col) * 64;

    floatx4 acc[4][4] = {};

#define CMP(BUF) do {                                                     \
        bf16x8 af[4][2], bfr[4][2];                                       \
        _Pragma("unroll") for (int mi = 0; mi < 4; mi++) {                \
            af[mi][0] = *(const bf16x8*)&As[BUF][aro[mi] + ko0];          \
            af[mi][1] = *(const bf16x8*)&As[BUF][aro[mi] + ko1]; }        \
        _Pragma("unroll") for (int ni = 0; ni < 4; ni++) {                \
            bfr[ni][0] = *(const bf16x8*)&Bs[BUF][bro[ni] + ko0];         \
            bfr[ni][1] = *(const bf16x8*)&Bs[BUF][bro[ni] + ko1]; }       \
        __builtin_amdgcn_s_setprio(1);                                    \
        _Pragma("unroll") for (int mi = 0; mi < 4; mi++)                  \
        _Pragma("unroll") for (int ni = 0; ni < 4; ni++) {                \
            acc[mi][ni] = mfma16(af[mi][0], bfr[ni][0], acc[mi][ni]);     \
            acc[mi][ni] = mfma16(af[mi][1], bfr[ni][1], acc[mi][ni]); }   \
        __builtin_amdgcn_s_setprio(0); } while (0)

    // prologue: tile 0 -> buf 0 (8 loads in flight)
    STG(0, 0);

    // main loop: 32 K-tiles of 64, alternating buffers. Invariants:
    //  - STG(t+1 -> other) issued right after the barrier that ended compute(t-1 from other)
    //  - vmcnt(8) retires tile t's 8 loads; tile t+1's 8 stay in flight across the barrier
    //  - wrap-stage at the end keeps the vmcnt arithmetic static (writes nothing reads)
#pragma unroll 1
    for (int tt = 0; tt < 16; tt++) {
        int t0k = tt * 2;
        STG(t0k + 1, 1);
        WVM8;
        G_SB; G_BAR; G_SB;
        CMP(0);
        G_SB; G_BAR;
        STG((t0k + 2) & 31, 0);
        WVM8;
        G_SB; G_BAR; G_SB;
        CMP(1);
        G_SB; G_BAR;
    }
    WVM0;   // drain wrap-staging before LDS goes out of scope

    // --- epilogue: bias add, bf16 convert, store. M exact -> no row guard.
    ushort_t* Cplain = z == 0 ? lqp : z == 2 ? lvp : llocp;
    int kcoff = (z == 4) ? 2048 : 0;
    bool to_kcat = (z == 1 || z == 4);
    float bvv[4];
#pragma unroll
    for (int ni = 0; ni < 4; ni++) bvv[ni] = bias[n0 + wc * 64 + ni * 16 + col];
#pragma unroll
    for (int mi = 0; mi < 4; mi++) {
#pragma unroll
        for (int r2 = 0; r2 < 4; r2++) {
            int m = m0 + wr * 64 + mi * 16 + quad * 4 + r2;
            ushort_t* crow;
            if (to_kcat) {
                int bb = m / 200, rr = m - bb * 200;
                crow = kcat + (size_t)(bb * 224 + rr) * 4096 + kcoff;
            } else {
                crow = Cplain + (size_t)m * 2048;
            }
#pragma unroll
            for (int ni = 0; ni < 4; ni++) {
                int n = n0 + wc * 64 + ni * 16 + col;
                crow[n] = f2bf(acc[mi][ni][r2] + bvv[ni]);
            }
        }
    }
#undef STG
#undef CMP
}

// ---------------- qcat[b][r][0:2048] = lq + param ; qcat[b][r][2048:] = lq + lloc
__global__ __launch_bounds__(256) void k_qprep(const ushort_t* __restrict__ lqp,
                                               const ushort_t* __restrict__ llocp,
                                               const float* __restrict__ param,
                                               ushort_t* __restrict__ qcat) {
    int m = blockIdx.x;           // 0..3199
    int b = m / 200, r = m - b * 200;
    int c = threadIdx.x * 8;
    bf16x8 ql = *(const bf16x8*)(lqp + (size_t)m * 2048 + c);
    bf16x8 ll = *(const bf16x8*)(llocp + (size_t)m * 2048 + c);
    floatx4 p0 = *(const floatx4*)(param + (size_t)m * 2048 + c);
    floatx4 p1 = *(const floatx4*)(param + (size_t)m * 2048 + c + 4);
    bf16x8 q1, q2;
#pragma unroll
    for (int j = 0; j < 4; j++) {
        q1[j]     = (__bf16)((float)ql[j] + p0[j]);
        q1[j + 4] = (__bf16)((float)ql[j + 4] + p1[j]);
        q2[j]     = (__bf16)((float)ql[j] + (float)ll[j]);
        q2[j + 4] = (__bf16)((float)ql[j + 4] + (float)ll[j + 4]);
    }
    ushort_t* dst = qcat + ((size_t)(b * 224 + r)) * 4096 + c;
    *(bf16x8*)dst = q1;
    *(bf16x8*)(dst + 2048) = q2;
}

// ---------------- Scores (K-split): part[kc][b][row 0..223][key 0..223] fp32 partial
// grid (7 qt x 16 b x 2 kc), 256 thr; 32 q-rows x 224 keys, K=2048 per block
__global__ __launch_bounds__(256) void k_scores(const ushort_t* __restrict__ qcat,
                                                const ushort_t* __restrict__ kcat,
                                                float* __restrict__ part) {
    int qt = blockIdx.x;   // 0..6
    int b  = blockIdx.y;   // 0..15
    int kc = blockIdx.z;   // 0..1
    __shared__ ushort_t As[32 * 32];    // 2 KB
    __shared__ ushort_t Bs[224 * 32];   // 14 KB

    int tid = threadIdx.x;
    int lane = tid & 63, w = tid >> 6;
    int quad = lane >> 4, col = lane & 15;
    int srow = lane >> 2, scol = (lane & 3) * 8;

    const ushort_t* qbase = qcat + ((size_t)b * 224 + qt * 32) * 4096 + kc * 2048;
    const ushort_t* kbase = kcat + (size_t)b * 224 * 4096 + kc * 2048;

    const ushort_t* ssrc[4];
    ushort_t* sdst[4];
#pragma unroll
    for (int o = 0; o < 4; o++) {
        int id = w * 4 + o;
        if (id < 14) {
            ssrc[o] = kbase + (size_t)(id * 16 + srow) * 4096 + scol;
            sdst[o] = Bs + id * 512;
        } else {
            ssrc[o] = qbase + (size_t)((id - 14) * 16 + srow) * 4096 + scol;
            sdst[o] = As + (id - 14) * 512;
        }
    }

    floatx4 acc[2][4] = {};
    for (int k0 = 0; k0 < 2048; k0 += 32) {
        __syncthreads();
#pragma unroll
        for (int o = 0; o < 4; o++) load_lds16(ssrc[o] + k0, sdst[o]);
        __syncthreads();
        bf16x8 af[2];
#pragma unroll
        for (int mi = 0; mi < 2; mi++) af[mi] = *(const bf16x8*)&As[(mi * 16 + col) * 32 + quad * 8];
#pragma unroll
        for (int fi = 0; fi < 4; fi++) {
            int f = w + fi * 4;
            if (f < 14) {
                bf16x8 bf = *(const bf16x8*)&Bs[(f * 16 + col) * 32 + quad * 8];
#pragma unroll
                for (int mi = 0; mi < 2; mi++) acc[mi][fi] = mfma16(af[mi], bf, acc[mi][fi]);
            }
        }
    }

    float* pbase = part + ((size_t)(kc * 16 + b) * 224 + qt * 32) * 224;
#pragma unroll
    for (int fi = 0; fi < 4; fi++) {
        int f = w + fi * 4;
        if (f < 14) {
#pragma unroll
            for (int mi = 0; mi < 2; mi++)
#pragma unroll
                for (int r = 0; r < 4; r++)
                    pbase[(mi * 16 + quad * 4 + r) * 224 + f * 16 + col] = acc[mi][fi][r];
        }
    }
}

// ---------------- softmax over summed partials -> attn bf16 [b][200][224], cols>=200 zero
// grid 400 blocks x 256 thr; 8 rows/block, 32 threads/row, 7 cols/thread
__global__ __launch_bounds__(256) void k_softmax(const float* __restrict__ part,
                                                 ushort_t* __restrict__ attn) {
    int row = blockIdx.x * 8 + (threadIdx.x >> 5);  // 0..3199
    int b = row / 200, r = row - b * 200;
    int p = threadIdx.x & 31;
    const float* p0 = part + ((size_t)b * 224 + r) * 224;
    const float* p1 = p0 + (size_t)16 * 224 * 224;
    const float scale = 0.022097086912079608f;  // 1/sqrt(2048)
    float ev[7];
    float mx = -1e30f;
#pragma unroll
    for (int j = 0; j < 7; j++) {
        int c = p * 7 + j;
        float v = (c < 200) ? (p0[c] + p1[c]) * scale : -1e30f;
        ev[j] = v;
        mx = fmaxf(mx, v);
    }
#pragma unroll
    for (int m = 1; m < 32; m <<= 1) mx = fmaxf(mx, __shfl_xor(mx, m, 32));
    float s = 0.f;
#pragma unroll
    for (int j = 0; j < 7; j++) {
        float e = __expf(ev[j] - mx);
        ev[j] = e;
        s += e;
    }
#pragma unroll
    for (int m = 1; m < 32; m <<= 1) s += __shfl_xor(s, m, 32);
    float rs = 1.0f / s;
    ushort_t* arow = attn + (size_t)row * 224;
#pragma unroll
    for (int j = 0; j < 7; j++) {
        int c = p * 7 + j;
        arow[c] = (c < 200) ? f2bf(ev[j] * rs) : (ushort_t)0;
    }
}

// ---------------- out[b][m][n] = attn[b][m][:] @ lv  (via lvT), fp32 out
__global__ __launch_bounds__(256) void k_pv(const ushort_t* __restrict__ attn,
                                            const ushort_t* __restrict__ lvT,
                                            float* __restrict__ out) {
    int nt = blockIdx.x;  // 0..15 (128 cols each)
    int qt = blockIdx.y;  // 0..12 (16 rows each)
    int b = blockIdx.z;
    int tid = threadIdx.x, lane = tid & 63, w = tid >> 6;
    int quad = lane >> 4, col = lane & 15;
    int aq = qt * 16 + col; if (aq > 199) aq = 199;
    const ushort_t* arow = attn + (size_t)(b * 200 + aq) * 224;
    int nbase = nt * 128 + w * 32;
    const ushort_t* bp0 = lvT + ((size_t)b * 2048 + nbase + col) * 224;
    const ushort_t* bp1 = lvT + ((size_t)b * 2048 + nbase + 16 + col) * 224;
    floatx4 acc[2] = {};
#pragma unroll
    for (int k0 = 0; k0 < 224; k0 += 32) {
        int ko = k0 + quad * 8;
        bf16x8 av = *(const bf16x8*)(arow + ko);
        bf16x8 b0 = *(const bf16x8*)(bp0 + ko);
        bf16x8 b1 = *(const bf16x8*)(bp1 + ko);
        acc[0] = mfma16(av, b0, acc[0]);
        acc[1] = mfma16(av, b1, acc[1]);
    }
#pragma unroll
    for (int f = 0; f < 2; f++) {
        int n = nbase + f * 16 + col;
#pragma unroll
        for (int r = 0; r < 4; r++) {
            int m = qt * 16 + quad * 4 + r;
            if (m < 200) out[(size_t)(b * 200 + m) * 2048 + n] = acc[f][r];
        }
    }
}

extern "C" void kernel_launch(void* const* d_in, const int* in_sizes, int n_in,
                              void* d_out, int out_size, void* d_ws, size_t ws_size,
                              hipStream_t stream) {
    (void)in_sizes; (void)n_in; (void)out_size; (void)ws_size;
    const float* q    = (const float*)d_in[0];
    const float* k    = (const float*)d_in[1];
    const float* v    = (const float*)d_in[2];
    const float* loc  = (const float*)d_in[3];
    const float* Wq   = (const float*)d_in[4];
    const float* bq   = (const float*)d_in[5];
    const float* Wk   = (const float*)d_in[6];
    const float* bk   = (const float*)d_in[7];
    const float* Wv   = (const float*)d_in[8];
    const float* bv   = (const float*)d_in[9];
    const float* Wloc = (const float*)d_in[10];
    const float* bloc = (const float*)d_in[11];
    const float* Wlk  = (const float*)d_in[12];
    const float* blk  = (const float*)d_in[13];
    const float* param = (const float*)d_in[14];
    float* out = (float*)d_out;

    size_t off = 0;
    auto nxt = [&](size_t bytes) {
        void* p = (char*)d_ws + off;
        off += (bytes + 255) & ~(size_t)255;
        return p;
    };
    ushort_t* wt[5];
    for (int i = 0; i < 5; i++) wt[i] = (ushort_t*)nxt(2048ull * 2048 * 2);
    ushort_t* qb    = (ushort_t*)nxt(3200ull * 2048 * 2);
    ushort_t* kb    = (ushort_t*)nxt(3200ull * 2048 * 2);
    ushort_t* vb    = (ushort_t*)nxt(3200ull * 2048 * 2);
    ushort_t* locb  = (ushort_t*)nxt(3200ull * 2048 * 2);
    ushort_t* lqp   = (ushort_t*)nxt(3200ull * 2048 * 2);
    ushort_t* llocp = (ushort_t*)nxt(3200ull * 2048 * 2);
    ushort_t* lvp   = (ushort_t*)nxt(3200ull * 2048 * 2);
    ushort_t* kcat  = (ushort_t*)nxt(16ull * 224 * 4096 * 2);
    // overlays (wt region = 41.9 MB, dead after k_gemm):
    ushort_t* lvT  = wt[0];                               // bytes 0 .. 14.7 MB
    ushort_t* attn = wt[0] + 16ull * 2048 * 224;          // 14.7 .. 16.1 MB
    float*    part = (float*)((char*)d_ws + 2ull * 2048 * 2048 * 2);  // 16.8 .. 23.2 MB (wt[2]+)
    ushort_t* qcat = qb;   // 29.4 MB into 52.4 MB conv region

    k_convert<<<dim3(6400, 4), 256, 0, stream>>>(q, k, v, loc, qb, kb, vb, locb);
    k_wtrans<<<dim3(64, 64, 5), 256, 0, stream>>>(Wq, Wk, Wv, Wloc, Wlk,
                                                  wt[0], wt[1], wt[2], wt[3], wt[4]);
    k_gemm<<<dim3(2000), 256, 0, stream>>>(qb, kb, vb, locb, locb,
                                           wt[0], wt[1], wt[2], wt[3], wt[4],
                                           bq, bk, bv, bloc, blk,
                                           lqp, lvp, llocp, kcat);
    k_qprep<<<dim3(3200), 256, 0, stream>>>(lqp, llocp, param, qcat);
    k_vtrans<<<dim3(64, 7, 16), 256, 0, stream>>>(lvp, lvT);
    k_scores<<<dim3(7, 16, 2), 256, 0, stream>>>(qcat, kcat, part);
    k_softmax<<<dim3(400), 256, 0, stream>>>(part, attn);
    k_pv<<<dim3(16, 13, 16), 256, 0, stream>>>(attn, lvT, out);
}

// Round 4
// 432.070 us; speedup vs baseline: 1.2395x; 1.0929x over previous
//
#include <hip/hip_runtime.h>
#include <hip/hip_bf16.h>
#include <math.h>

typedef float floatx4 __attribute__((ext_vector_type(4)));
typedef __bf16 bf16x8 __attribute__((ext_vector_type(8)));
typedef unsigned short ushort_t;

__device__ __forceinline__ ushort_t f2bf(float f) {
    union { float f; unsigned int i; } v; v.f = f;
    unsigned int i = v.i;
    return (ushort_t)((i + 0x7FFFu + ((i >> 16) & 1u)) >> 16);  // RNE, inputs finite
}
__device__ __forceinline__ unsigned int pack2(float a, float b) {
    return (unsigned int)f2bf(a) | ((unsigned int)f2bf(b) << 16);
}
__device__ __forceinline__ floatx4 mfma16(bf16x8 a, bf16x8 b, floatx4 c) {
    return __builtin_amdgcn_mfma_f32_16x16x32_bf16(a, b, c, 0, 0, 0);
}
// async global->LDS, 16B/lane; g is PER-LANE address, lds base wave-uniform,
// lane i lands at lds_base + i*16 bytes
__device__ __forceinline__ void load_lds16(const ushort_t* g, ushort_t* l) {
    __builtin_amdgcn_global_load_lds(
        (const __attribute__((address_space(1))) unsigned int*)g,
        (__attribute__((address_space(3))) unsigned int*)l, 16, 0, 0);
}

#define G_SB   __builtin_amdgcn_sched_barrier(0)
#define G_BAR  __builtin_amdgcn_s_barrier()
#define WVM8   asm volatile("s_waitcnt vmcnt(8)" ::: "memory")
#define WVM0   asm volatile("s_waitcnt vmcnt(0)" ::: "memory")

// ---------------- fp32 -> bf16 conversion of activations (q,k,v,loc), 3200x2048 each
__global__ __launch_bounds__(256) void k_convert(const float* __restrict__ q, const float* __restrict__ k,
                          const float* __restrict__ v, const float* __restrict__ loc,
                          ushort_t* qb, ushort_t* kb, ushort_t* vb, ushort_t* locb) {
    int z = blockIdx.y;
    const float* src = z == 0 ? q : z == 1 ? k : z == 2 ? v : loc;
    ushort_t* dst    = z == 0 ? qb : z == 1 ? kb : z == 2 ? vb : locb;
    size_t idx = (size_t)blockIdx.x * 256 + threadIdx.x;
    floatx4 f = *(const floatx4*)(src + idx * 4);
    uint2 o;
    o.x = pack2(f[0], f[1]);
    o.y = pack2(f[2], f[3]);
    *(uint2*)(dst + idx * 4) = o;
}

// ---------------- Weight transpose+convert: W (2048x2048 fp32, KxN) -> Wt (NxK bf16)
__global__ void k_wtrans(const float* __restrict__ w0, const float* __restrict__ w1,
                         const float* __restrict__ w2, const float* __restrict__ w3,
                         const float* __restrict__ w4,
                         ushort_t* t0, ushort_t* t1, ushort_t* t2, ushort_t* t3, ushort_t* t4) {
    __shared__ float tile[32][33];
    int z = blockIdx.z;
    const float* W = z == 0 ? w0 : z == 1 ? w1 : z == 2 ? w2 : z == 3 ? w3 : w4;
    ushort_t* T    = z == 0 ? t0 : z == 1 ? t1 : z == 2 ? t2 : z == 3 ? t3 : t4;
    int n0 = blockIdx.x * 32, k0 = blockIdx.y * 32;
    int tx = threadIdx.x & 31, ty = threadIdx.x >> 5;
#pragma unroll
    for (int i = 0; i < 4; i++) {
        int row = ty + i * 8;
        tile[row][tx] = W[(size_t)(k0 + row) * 2048 + n0 + tx];
    }
    __syncthreads();
#pragma unroll
    for (int i = 0; i < 4; i++) {
        int row = ty + i * 8;
        T[(size_t)(n0 + row) * 2048 + k0 + tx] = f2bf(tile[tx][row]);
    }
}

// ---------------- lv (3200x2048 bf16) -> lvT ([b][h][t] padded t->224, zeros)
__global__ void k_vtrans(const ushort_t* __restrict__ lv, ushort_t* __restrict__ lvT) {
    __shared__ ushort_t tile[32][33];
    int n0 = blockIdx.x * 32;
    int t0 = blockIdx.y * 32;
    int b = blockIdx.z;
    int tx = threadIdx.x & 31, ty = threadIdx.x >> 5;
#pragma unroll
    for (int i = 0; i < 4; i++) {
        int row = ty + i * 8;
        int tk = t0 + row;
        ushort_t v = 0;
        if (tk < 200) v = lv[(size_t)(b * 200 + tk) * 2048 + n0 + tx];
        tile[row][tx] = v;
    }
    __syncthreads();
#pragma unroll
    for (int i = 0; i < 4; i++) {
        int row = ty + i * 8;
        lvT[((size_t)b * 2048 + n0 + row) * 224 + t0 + tx] = tile[tx][row];
    }
}

// ---------------- Batched projection GEMM — 128x128 tile (tail-free fine grid), BK=64,
// 64 KiB LDS double-buffer -> 2 blocks/CU, 4 waves (2M x 2N), counted vmcnt(8) (never 0
// in the loop), XOR-swizzled LDS (0 bank conflicts), XCD-aware swizzle.
// M = 3200 = 25x128 exactly. Grid 2000 = 25m x 16n x 5z = 8 XCDs x 250.
// z=0 -> lqp, z=1 -> kcat[:, 0:2048], z=2 -> lvp, z=3 -> llocp, z=4 -> kcat[:, 2048:4096]
__global__ __launch_bounds__(256, 2) void k_gemm(
    const ushort_t* A0, const ushort_t* A1, const ushort_t* A2, const ushort_t* A3, const ushort_t* A4,
    const ushort_t* W0, const ushort_t* W1, const ushort_t* W2, const ushort_t* W3, const ushort_t* W4,
    const float* B0, const float* B1, const float* B2, const float* B3, const float* B4,
    ushort_t* lqp, ushort_t* lvp, ushort_t* llocp, ushort_t* kcat) {
    // 2000 blocks = 8 XCDs x 250; bijective. Within an XCD: m-tiles fastest (25 per
    // n-panel) so the 0.5 MB B-panel stays L2-resident across 25 consecutive blocks.
    int bid = blockIdx.x;
    int tileid = (bid & 7) * 250 + (bid >> 3);
    int z = tileid / 400;              // 25 m x 16 n = 400 tiles per z
    int r = tileid - z * 400;
    int nt = r / 25;
    int mt = r - nt * 25;
    int m0 = mt * 128, n0 = nt * 128;

    const ushort_t* A  = z == 0 ? A0 : z == 1 ? A1 : z == 2 ? A2 : z == 3 ? A3 : A4;
    const ushort_t* Wt = z == 0 ? W0 : z == 1 ? W1 : z == 2 ? W2 : z == 3 ? W3 : W4;
    const float* bias  = z == 0 ? B0 : z == 1 ? B1 : z == 2 ? B2 : z == 3 ? B3 : B4;

    __shared__ ushort_t As[2][128 * 64];   // 16 KB each buffer
    __shared__ ushort_t Bs[2][128 * 64];

    int tid = threadIdx.x;
    int lane = tid & 63, w = tid >> 6;
    int quad = lane >> 4, col = lane & 15;
    int wr = w >> 1, wc = w & 1;

    // --- staging: per gload one wave covers 8 rows x 128 B. XOR swizzle (chunk ^= row&7)
    // applied on the GLOBAL source address; LDS written linearly.
    int sl = lane >> 3;
    int sc = ((lane & 7) ^ sl) * 8;        // element offset of swizzled 16B chunk
    const ushort_t* Ag[4]; const ushort_t* Bg[4]; int ldst[4];
#pragma unroll
    for (int u = 0; u < 4; u++) {
        int rowoff = u * 32 + w * 8;
        Ag[u] = A  + (size_t)(m0 + rowoff + sl) * 2048 + sc;
        Bg[u] = Wt + (size_t)(n0 + rowoff + sl) * 2048 + sc;
        ldst[u] = rowoff * 64;             // element offset inside one buffer
    }

#define STG(KT, BUF) do { int kk = (KT) * 64;              \
        load_lds16(Ag[0] + kk, As[BUF] + ldst[0]);         \
        load_lds16(Ag[1] + kk, As[BUF] + ldst[1]);         \
        load_lds16(Ag[2] + kk, As[BUF] + ldst[2]);         \
        load_lds16(Ag[3] + kk, As[BUF] + ldst[3]);         \
        load_lds16(Bg[0] + kk, Bs[BUF] + ldst[0]);         \
        load_lds16(Bg[1] + kk, Bs[BUF] + ldst[1]);         \
        load_lds16(Bg[2] + kk, Bs[BUF] + ldst[2]);         \
        load_lds16(Bg[3] + kk, Bs[BUF] + ldst[3]); } while (0)

    // --- ds_read offsets. frag(row, ks): elem row*64 + ((ks*4+quad)^(col&7))*8.
    int sw = col & 7;
    int ko0 = (quad ^ sw) * 8;
    int ko1 = ((4 | quad) ^ sw) * 8;
    int aro[4], bro[4];
#pragma unroll
    for (int mi = 0; mi < 4; mi++) aro[mi] = (wr * 64 + mi * 16 + col) * 64;
#pragma unroll
    for (int ni = 0; ni < 4; ni++) bro[ni] = (wc * 64 + ni * 16 + col) * 64;

    floatx4 acc[4][4] = {};

#define CMP(BUF) do {                                                     \
        bf16x8 af[4][2], bfr[4][2];                                       \
        _Pragma("unroll") for (int mi = 0; mi < 4; mi++) {                \
            af[mi][0] = *(const bf16x8*)&As[BUF][aro[mi] + ko0];          \
            af[mi][1] = *(const bf16x8*)&As[BUF][aro[mi] + ko1]; }        \
        _Pragma("unroll") for (int ni = 0; ni < 4; ni++) {                \
            bfr[ni][0] = *(const bf16x8*)&Bs[BUF][bro[ni] + ko0];         \
            bfr[ni][1] = *(const bf16x8*)&Bs[BUF][bro[ni] + ko1]; }       \
        __builtin_amdgcn_s_setprio(1);                                    \
        _Pragma("unroll") for (int mi = 0; mi < 4; mi++)                  \
        _Pragma("unroll") for (int ni = 0; ni < 4; ni++) {                \
            acc[mi][ni] = mfma16(af[mi][0], bfr[ni][0], acc[mi][ni]);     \
            acc[mi][ni] = mfma16(af[mi][1], bfr[ni][1], acc[mi][ni]); }   \
        __builtin_amdgcn_s_setprio(0); } while (0)

    STG(0, 0);
#pragma unroll 1
    for (int tt = 0; tt < 16; tt++) {
        int t0k = tt * 2;
        STG(t0k + 1, 1);
        WVM8;
        G_SB; G_BAR; G_SB;
        CMP(0);
        G_SB; G_BAR;
        STG((t0k + 2) & 31, 0);
        WVM8;
        G_SB; G_BAR; G_SB;
        CMP(1);
        G_SB; G_BAR;
    }
    WVM0;   // drain wrap-staging before LDS goes out of scope

    // --- epilogue: bias add, bf16 convert, store. M exact -> no row guard.
    ushort_t* Cplain = z == 0 ? lqp : z == 2 ? lvp : llocp;
    int kcoff = (z == 4) ? 2048 : 0;
    bool to_kcat = (z == 1 || z == 4);
    float bvv[4];
#pragma unroll
    for (int ni = 0; ni < 4; ni++) bvv[ni] = bias[n0 + wc * 64 + ni * 16 + col];
#pragma unroll
    for (int mi = 0; mi < 4; mi++) {
#pragma unroll
        for (int r2 = 0; r2 < 4; r2++) {
            int m = m0 + wr * 64 + mi * 16 + quad * 4 + r2;
            ushort_t* crow;
            if (to_kcat) {
                int bb = m / 200, rr = m - bb * 200;
                crow = kcat + (size_t)(bb * 224 + rr) * 4096 + kcoff;
            } else {
                crow = Cplain + (size_t)m * 2048;
            }
#pragma unroll
            for (int ni = 0; ni < 4; ni++) {
                int n = n0 + wc * 64 + ni * 16 + col;
                crow[n] = f2bf(acc[mi][ni][r2] + bvv[ni]);
            }
        }
    }
#undef STG
#undef CMP
}

// ---------------- qcat[b][r][0:2048] = lq + param ; qcat[b][r][2048:] = lq + lloc
__global__ __launch_bounds__(256) void k_qprep(const ushort_t* __restrict__ lqp,
                                               const ushort_t* __restrict__ llocp,
                                               const float* __restrict__ param,
                                               ushort_t* __restrict__ qcat) {
    int m = blockIdx.x;           // 0..3199
    int b = m / 200, r = m - b * 200;
    int c = threadIdx.x * 8;
    bf16x8 ql = *(const bf16x8*)(lqp + (size_t)m * 2048 + c);
    bf16x8 ll = *(const bf16x8*)(llocp + (size_t)m * 2048 + c);
    floatx4 p0 = *(const floatx4*)(param + (size_t)m * 2048 + c);
    floatx4 p1 = *(const floatx4*)(param + (size_t)m * 2048 + c + 4);
    bf16x8 q1, q2;
#pragma unroll
    for (int j = 0; j < 4; j++) {
        q1[j]     = (__bf16)((float)ql[j] + p0[j]);
        q1[j + 4] = (__bf16)((float)ql[j + 4] + p1[j]);
        q2[j]     = (__bf16)((float)ql[j] + (float)ll[j]);
        q2[j + 4] = (__bf16)((float)ql[j + 4] + (float)ll[j + 4]);
    }
    ushort_t* dst = qcat + ((size_t)(b * 224 + r)) * 4096 + c;
    *(bf16x8*)dst = q1;
    *(bf16x8*)(dst + 2048) = q2;
}

// ---------------- Scores (4-way K-split): part[kc][b][row][key] fp32 partial.
// 448 blocks = 8 XCDs x 56 (bijective); idx within XCD is qt-fastest so all 7 qt blocks
// of one (b,kc) share the kcat K-panel in that XCD's L2. BK=64 double-buffer (64 KB LDS,
// 2 blocks/CU), source-side XOR swizzle (2 lanes/bank), counted vmcnt(8), raw s_barrier.
__global__ __launch_bounds__(256, 2) void k_scores(const ushort_t* __restrict__ qcat,
                                                   const ushort_t* __restrict__ kcat,
                                                   float* __restrict__ part) {
    int bid = blockIdx.x;
    int tile = (bid & 7) * 56 + (bid >> 3);
    int qt = tile % 7;           // 0..6   (32 q-rows)
    int t2 = tile / 7;
    int b  = t2 & 15;            // 0..15
    int kc = t2 >> 4;            // 0..3   (K-chunk of 1024)

    __shared__ ushort_t S[2][256 * 64];   // rows 0..31 = q, rows 32..255 = k; 32 KB/buf

    int tid = threadIdx.x;
    int lane = tid & 63, w = tid >> 6;
    int quad = lane >> 4, col = lane & 15;

    int sl = lane >> 3;
    int sc = ((lane & 7) ^ sl) * 8;       // pre-swizzled 16B chunk (element offset)

    const ushort_t* qbase = qcat + ((size_t)b * 224 + qt * 32) * 4096 + kc * 1024;
    const ushort_t* kbase = kcat + (size_t)b * 224 * 4096 + kc * 1024;

    const ushort_t* gsrc[8]; int ldst[8];
#pragma unroll
    for (int u = 0; u < 8; u++) {
        int row = u * 32 + w * 8;         // block row (0..255), 8-row slab per wave
        gsrc[u] = (u == 0) ? qbase + (size_t)(row + sl) * 4096 + sc
                           : kbase + (size_t)(row - 32 + sl) * 4096 + sc;
        ldst[u] = row * 64;
    }

#define SSTG(KT, BUF) do { int kk = (KT) * 64;                        \
        _Pragma("unroll") for (int u = 0; u < 8; u++)                 \
            load_lds16(gsrc[u] + kk, S[BUF] + ldst[u]); } while (0)

    int sw = col & 7;
    int ko0 = (quad ^ sw) * 8;
    int ko1 = ((4 | quad) ^ sw) * 8;

    floatx4 acc[2][4] = {};

#define SCMP(BUF) do {                                                    \
        bf16x8 af[2][2];                                                  \
        _Pragma("unroll") for (int mi = 0; mi < 2; mi++) {                \
            int ar = (mi * 16 + col) * 64;                                \
            af[mi][0] = *(const bf16x8*)&S[BUF][ar + ko0];                \
            af[mi][1] = *(const bf16x8*)&S[BUF][ar + ko1]; }              \
        __builtin_amdgcn_s_setprio(1);                                    \
        _Pragma("unroll") for (int fi = 0; fi < 4; fi++) {                \
            int f = w + fi * 4;                                           \
            if (f < 14) {                                                 \
                int br = (32 + f * 16 + col) * 64;                        \
                bf16x8 b0 = *(const bf16x8*)&S[BUF][br + ko0];            \
                bf16x8 b1 = *(const bf16x8*)&S[BUF][br + ko1];            \
                _Pragma("unroll") for (int mi = 0; mi < 2; mi++) {        \
                    acc[mi][fi] = mfma16(af[mi][0], b0, acc[mi][fi]);     \
                    acc[mi][fi] = mfma16(af[mi][1], b1, acc[mi][fi]); }   \
            } }                                                           \
        __builtin_amdgcn_s_setprio(0); } while (0)

    SSTG(0, 0);
#pragma unroll 1
    for (int tt = 0; tt < 8; tt++) {
        SSTG(2 * tt + 1, 1);
        WVM8; G_SB; G_BAR; G_SB;
        SCMP(0);
        G_SB; G_BAR;
        SSTG((2 * tt + 2) & 15, 0);
        WVM8; G_SB; G_BAR; G_SB;
        SCMP(1);
        G_SB; G_BAR;
    }
    WVM0;

    float* pbase = part + ((size_t)(kc * 16 + b) * 224 + qt * 32) * 224;
#pragma unroll
    for (int fi = 0; fi < 4; fi++) {
        int f = w + fi * 4;
        if (f < 14) {
#pragma unroll
            for (int mi = 0; mi < 2; mi++)
#pragma unroll
                for (int r = 0; r < 4; r++)
                    pbase[(mi * 16 + quad * 4 + r) * 224 + f * 16 + col] = acc[mi][fi][r];
        }
    }
#undef SSTG
#undef SCMP
}

// ---------------- softmax over 4 summed partials -> attn bf16 [b][200][224], cols>=200 zero
// grid 400 blocks x 256 thr; 8 rows/block, 32 threads/row, 7 cols/thread
__global__ __launch_bounds__(256) void k_softmax(const float* __restrict__ part,
                                                 ushort_t* __restrict__ attn) {
    int row = blockIdx.x * 8 + (threadIdx.x >> 5);  // 0..3199
    int b = row / 200, r = row - b * 200;
    int p = threadIdx.x & 31;
    const float* p0 = part + ((size_t)b * 224 + r) * 224;
    const size_t st = (size_t)16 * 224 * 224;
    const float scale = 0.022097086912079608f;  // 1/sqrt(2048)
    float ev[7];
    float mx = -1e30f;
#pragma unroll
    for (int j = 0; j < 7; j++) {
        int c = p * 7 + j;
        float v = (c < 200) ? (p0[c] + p0[c + st] + p0[c + 2 * st] + p0[c + 3 * st]) * scale
                            : -1e30f;
        ev[j] = v;
        mx = fmaxf(mx, v);
    }
#pragma unroll
    for (int m = 1; m < 32; m <<= 1) mx = fmaxf(mx, __shfl_xor(mx, m, 32));
    float s = 0.f;
#pragma unroll
    for (int j = 0; j < 7; j++) {
        float e = __expf(ev[j] - mx);
        ev[j] = e;
        s += e;
    }
#pragma unroll
    for (int m = 1; m < 32; m <<= 1) s += __shfl_xor(s, m, 32);
    float rs = 1.0f / s;
    ushort_t* arow = attn + (size_t)row * 224;
#pragma unroll
    for (int j = 0; j < 7; j++) {
        int c = p * 7 + j;
        arow[c] = (c < 200) ? f2bf(ev[j] * rs) : (ushort_t)0;
    }
}

// ---------------- out[b][m][n] = attn[b][m][:] @ lv (via lvT), fp32 out.
// 32 q-rows x 256 n-cols per block; grid (8 nt, 7 qt, 16 b) = 896 blocks, 4 waves
// (one 64-col slab each). lvT re-read 7x (was 13x); no LDS (K=224 only).
__global__ __launch_bounds__(256) void k_pv(const ushort_t* __restrict__ attn,
                                            const ushort_t* __restrict__ lvT,
                                            float* __restrict__ out) {
    int nt = blockIdx.x;  // 0..7 (256 cols each)
    int qt = blockIdx.y;  // 0..6 (32 rows each)
    int b = blockIdx.z;
    int tid = threadIdx.x, lane = tid & 63, w = tid >> 6;
    int quad = lane >> 4, col = lane & 15;
    const ushort_t* arow[2];
#pragma unroll
    for (int mi = 0; mi < 2; mi++) {
        int aq = qt * 32 + mi * 16 + col; if (aq > 199) aq = 199;
        arow[mi] = attn + (size_t)(b * 200 + aq) * 224;
    }
    int nbase = nt * 256 + w * 64;
    const ushort_t* bp[4];
#pragma unroll
    for (int ni = 0; ni < 4; ni++)
        bp[ni] = lvT + ((size_t)b * 2048 + nbase + ni * 16 + col) * 224;
    floatx4 acc[2][4] = {};
#pragma unroll
    for (int k0 = 0; k0 < 224; k0 += 32) {
        int ko = k0 + quad * 8;
        bf16x8 av[2];
#pragma unroll
        for (int mi = 0; mi < 2; mi++) av[mi] = *(const bf16x8*)(arow[mi] + ko);
#pragma unroll
        for (int ni = 0; ni < 4; ni++) {
            bf16x8 bv = *(const bf16x8*)(bp[ni] + ko);
#pragma unroll
            for (int mi = 0; mi < 2; mi++) acc[mi][ni] = mfma16(av[mi], bv, acc[mi][ni]);
        }
    }
#pragma unroll
    for (int mi = 0; mi < 2; mi++) {
#pragma unroll
        for (int r = 0; r < 4; r++) {
            int m = qt * 32 + mi * 16 + quad * 4 + r;
            if (m < 200) {
#pragma unroll
                for (int ni = 0; ni < 4; ni++) {
                    int n = nbase + ni * 16 + col;
                    out[(size_t)(b * 200 + m) * 2048 + n] = acc[mi][ni][r];
                }
            }
        }
    }
}

extern "C" void kernel_launch(void* const* d_in, const int* in_sizes, int n_in,
                              void* d_out, int out_size, void* d_ws, size_t ws_size,
                              hipStream_t stream) {
    (void)in_sizes; (void)n_in; (void)out_size; (void)ws_size;
    const float* q    = (const float*)d_in[0];
    const float* k    = (const float*)d_in[1];
    const float* v    = (const float*)d_in[2];
    const float* loc  = (const float*)d_in[3];
    const float* Wq   = (const float*)d_in[4];
    const float* bq   = (const float*)d_in[5];
    const float* Wk   = (const float*)d_in[6];
    const float* bk   = (const float*)d_in[7];
    const float* Wv   = (const float*)d_in[8];
    const float* bv   = (const float*)d_in[9];
    const float* Wloc = (const float*)d_in[10];
    const float* bloc = (const float*)d_in[11];
    const float* Wlk  = (const float*)d_in[12];
    const float* blk  = (const float*)d_in[13];
    const float* param = (const float*)d_in[14];
    float* out = (float*)d_out;

    size_t off = 0;
    auto nxt = [&](size_t bytes) {
        void* p = (char*)d_ws + off;
        off += (bytes + 255) & ~(size_t)255;
        return p;
    };
    ushort_t* wt[5];
    for (int i = 0; i < 5; i++) wt[i] = (ushort_t*)nxt(2048ull * 2048 * 2);
    ushort_t* qb    = (ushort_t*)nxt(3200ull * 2048 * 2);
    ushort_t* kb    = (ushort_t*)nxt(3200ull * 2048 * 2);
    ushort_t* vb    = (ushort_t*)nxt(3200ull * 2048 * 2);
    ushort_t* locb  = (ushort_t*)nxt(3200ull * 2048 * 2);
    ushort_t* lqp   = (ushort_t*)nxt(3200ull * 2048 * 2);
    ushort_t* llocp = (ushort_t*)nxt(3200ull * 2048 * 2);
    ushort_t* lvp   = (ushort_t*)nxt(3200ull * 2048 * 2);
    ushort_t* kcat  = (ushort_t*)nxt(16ull * 224 * 4096 * 2);
    // overlays (wt region = 41.9 MB, dead after k_gemm):
    ushort_t* lvT  = wt[0];                               // 0 .. 14.68 MB
    ushort_t* attn = wt[0] + 16ull * 2048 * 224;          // 14.68 .. 16.11 MB
    float*    part = (float*)(attn + 3200ull * 224);      // 16.11 .. 28.96 MB (4 kc slabs)
    ushort_t* qcat = qb;   // 29.4 MB into 52.4 MB conv region

    k_convert<<<dim3(6400, 4), 256, 0, stream>>>(q, k, v, loc, qb, kb, vb, locb);
    k_wtrans<<<dim3(64, 64, 5), 256, 0, stream>>>(Wq, Wk, Wv, Wloc, Wlk,
                                                  wt[0], wt[1], wt[2], wt[3], wt[4]);
    k_gemm<<<dim3(2000), 256, 0, stream>>>(qb, kb, vb, locb, locb,
                                           wt[0], wt[1], wt[2], wt[3], wt[4],
                                           bq, bk, bv, bloc, blk,
                                           lqp, lvp, llocp, kcat);
    k_qprep<<<dim3(3200), 256, 0, stream>>>(lqp, llocp, param, qcat);
    k_vtrans<<<dim3(64, 7, 16), 256, 0, stream>>>(lvp, lvT);
    k_scores<<<dim3(448), 256, 0, stream>>>(qcat, kcat, part);
    k_softmax<<<dim3(400), 256, 0, stream>>>(part, attn);
    k_pv<<<dim3(8, 7, 16), 256, 0, stream>>>(attn, lvT, out);
}